// Round 4
// baseline (2164.548 us; speedup 1.0000x reference)
//
#include <hip/hip_runtime.h>
#include <hip/hip_bf16.h>
#include <stdint.h>

typedef __hip_bfloat16 bf16;

#define NB 1024
#define NM 4096
#define NZ 64
#define NH 8192

// flag: 1 = buffers are float32, 0 = buffers are bf16
__device__ __forceinline__ float ldx(const void* p, size_t i, int f) {
  return f ? ((const float*)p)[i] : __bfloat162float(((const bf16*)p)[i]);
}
__device__ __forceinline__ void stx(void* p, size_t i, int f, float v) {
  if (f) ((float*)p)[i] = v;
  else   ((bf16*)p)[i] = __float2bfloat16(v);
}
__device__ __forceinline__ float sigf(float x) { return 1.f / (1.f + __expf(-x)); }

// ---------------------------------------------------------------------------
// Input-dtype probe. Read x (values ~N(0,1)) as 32-bit words.
//   true fp32 : bits 22..7 are mantissa noise -> (w>>7)&0xFF uniform (~12% in band)
//   bf16 pair : bits 22..7 contain the LOW bf16's sign+exponent -> (w>>7)&0xFF
//               is that bf16's exponent, concentrated in [110,130] (~99%)
// ---------------------------------------------------------------------------
__global__ void detect_dtype(const uint32_t* __restrict__ x, int* __restrict__ flag) {
  __shared__ int s;
  if (threadIdx.x == 0) s = 0;
  __syncthreads();
  int c = 0;
  for (int i = threadIdx.x; i < 1024; i += 256) {
    const int e = (x[i] >> 7) & 0xFF;   // low-half "exponent" byte
    if (e >= 100 && e <= 135) c++;
  }
  atomicAdd(&s, c);
  __syncthreads();
  if (threadIdx.x == 0) *flag = (s > 512) ? 0 /*bf16*/ : 1 /*fp32*/;
}

// ---------------------------------------------------------------------------
// Simple tiled VALU NT GEMM (correctness-first; no MFMA this round).
// C[r,c] = act( sum_k A[r,k] * W[c,k] + bias[c] ), fp32 accumulate in LDS/regs.
// Tile 64x64, BK=16, 256 threads, 4x4 accumulators/thread.
// W row select: rows >= wsplit come from Wp2 (for the mu/lv concat case).
// OUTF32: write fp32 to Cf (internal buffer) instead of flag-dtype C.
// ---------------------------------------------------------------------------
template<int ACT, int OUTF32>
__global__ __launch_bounds__(256) void gemm_tiled(
    const void* __restrict__ A, size_t aoff,
    const void* __restrict__ Wp, const void* __restrict__ Wp2, int wsplit,
    const void* __restrict__ bias,
    void* __restrict__ C, size_t coff, float* __restrict__ Cf,
    int K, int N, const int* __restrict__ flag) {
  const int f = *flag;
  __shared__ __attribute__((aligned(16))) float sA[16][68];  // 68: 16B-aligned rows
  __shared__ __attribute__((aligned(16))) float sW[16][68];
  const int tid = threadIdx.x;
  const int tx = tid & 15, ty = tid >> 4;
  const int row0 = blockIdx.x * 64, col0 = blockIdx.y * 64;

  float acc[4][4];
#pragma unroll
  for (int i = 0; i < 4; i++)
#pragma unroll
    for (int j = 0; j < 4; j++) acc[i][j] = 0.f;

  for (int k0 = 0; k0 < K; k0 += 16) {
    __syncthreads();
#pragma unroll
    for (int q = 0; q < 4; q++) {
      const int idx = tid + q * 256;       // 0..1023
      const int kk = idx & 15;             // k within tile
      const int r  = idx >> 4;             // row within tile (consecutive lanes -> consecutive k: coalesced)
      sA[kk][r] = ldx(A, aoff + (size_t)(row0 + r) * K + (k0 + kk), f);
      const int wr = col0 + r;
      const void* wp = (wr < wsplit) ? Wp : Wp2;
      const int wrr  = (wr < wsplit) ? wr : wr - wsplit;
      sW[kk][r] = ldx(wp, (size_t)wrr * K + (k0 + kk), f);
    }
    __syncthreads();
#pragma unroll
    for (int k = 0; k < 16; k++) {
      float a[4], w[4];
      *(float4*)a = *(const float4*)&sA[k][ty * 4];
      *(float4*)w = *(const float4*)&sW[k][tx * 4];
#pragma unroll
      for (int i = 0; i < 4; i++)
#pragma unroll
        for (int j = 0; j < 4; j++) acc[i][j] += a[i] * w[j];
    }
  }

#pragma unroll
  for (int j = 0; j < 4; j++) {
    const int cc = col0 + tx * 4 + j;
    const float bs = bias ? ldx(bias, cc, f) : 0.f;
#pragma unroll
    for (int i = 0; i < 4; i++) {
      const int rr = row0 + ty * 4 + i;
      float v = acc[i][j] + bs;
      if (ACT == 1) v = v > 0.f ? v : 0.f;
      if (ACT == 2) v = sigf(v);
      if (OUTF32) Cf[(size_t)rr * N + cc] = v;
      else        stx(C, coff + (size_t)rr * N + cc, f, v);
    }
  }
}

// ---------------------------------------------------------------------------
// mu/lv bias + reparameterization. zpre fp32 [B][128] (cols 0..63 mu-pre,
// 64..127 lv-pre). Writes mu/logvar (flag dtype into d_out) and z (fp32 ws).
// ---------------------------------------------------------------------------
__global__ void zfin(const float* __restrict__ zpre, const void* __restrict__ eps,
                     const void* __restrict__ mub, const void* __restrict__ lvb,
                     void* __restrict__ dout, float* __restrict__ z,
                     const int* __restrict__ flag) {
  const int f = *flag;
  const int i = blockIdx.x * 256 + threadIdx.x;   // B*Z = 65536
  const int b = i >> 6, j = i & 63;
  const float mu = zpre[(size_t)b * 128 + j] + ldx(mub, j, f);
  const float lv = zpre[(size_t)b * 128 + 64 + j] + ldx(lvb, j, f);
  const float zz = mu + expf(0.5f * lv) * ldx(eps, i, f);
  stx(dout, (size_t)2 * NB * NM + i, f, mu);                    // out_mu
  stx(dout, (size_t)2 * NB * NM + (size_t)NB * NZ + i, f, lv);  // out_lv
  z[i] = zz;
}

// ---------------------------------------------------------------------------
// Fused decoder branch: fulcon sigmoid + two 2x2 sigmoid block layers + out dot.
// z fp32 internal. Block covers 64 b x 256 m; grid (16,16).
// ---------------------------------------------------------------------------
__global__ __launch_bounds__(256) void dec_fused(
    const float* __restrict__ z,
    const void* __restrict__ fw, const void* __restrict__ fb,
    const void* __restrict__ hw, const void* __restrict__ hb,
    const void* __restrict__ ow, const void* __restrict__ ob,
    void* __restrict__ dout, size_t ooff, const int* __restrict__ flag) {
  const int f = *flag;
  __shared__ float sZ[64][65];     // [k][b], padded
  const int tid = threadIdx.x;
  const int b0 = blockIdx.x * 64;
  const int m0 = blockIdx.y * 256;
  {
    const int r  = tid >> 2;          // b-row 0..63
    const int c0 = (tid & 3) * 16;    // k-chunk
    const float* p = z + (size_t)(b0 + r) * NZ + c0;
#pragma unroll
    for (int i = 0; i < 16; i++) sZ[c0 + i][r] = p[i];
  }
  __syncthreads();

  const int bq = tid >> 6;   // 0..3 : 16-b group
  const int tm = tid & 63;   // lane -> consecutive m

  for (int mi = 0; mi < 4; mi++) {
    const int m = m0 + mi * 64 + tm;
    float acc0[16], acc1[16];
    const float bb0 = ldx(fb, 2 * m, f), bb1 = ldx(fb, 2 * m + 1, f);
#pragma unroll
    for (int b = 0; b < 16; b++) { acc0[b] = bb0; acc1[b] = bb1; }
#pragma unroll 8
    for (int k = 0; k < 64; k++) {
      const float w0 = ldx(fw, (size_t)(2 * m) * NZ + k, f);
      const float w1 = ldx(fw, (size_t)(2 * m + 1) * NZ + k, f);
      const float* zrow = &sZ[k][bq * 16];
#pragma unroll
      for (int b = 0; b < 16; b++) {
        acc0[b] += zrow[b] * w0;
        acc1[b] += zrow[b] * w1;
      }
    }
    float wv[2][4], hbv[2][2];
#pragma unroll
    for (int l = 0; l < 2; l++) {
      const size_t wb = ((size_t)l * NM + m) * 4;   // [v][w] 2x2
      wv[l][0] = ldx(hw, wb + 0, f); wv[l][1] = ldx(hw, wb + 1, f);
      wv[l][2] = ldx(hw, wb + 2, f); wv[l][3] = ldx(hw, wb + 3, f);
      hbv[l][0] = ldx(hb, (size_t)l * NH + 2 * m, f);
      hbv[l][1] = ldx(hb, (size_t)l * NH + 2 * m + 1, f);
    }
    const float o0 = ldx(ow, 2 * m, f), o1 = ldx(ow, 2 * m + 1, f), obv = ldx(ob, m, f);
#pragma unroll
    for (int b = 0; b < 16; b++) {
      float a0 = sigf(acc0[b]), a1 = sigf(acc1[b]);
#pragma unroll
      for (int l = 0; l < 2; l++) {
        const float v0 = sigf(wv[l][0] * a0 + wv[l][1] * a1 + hbv[l][0]);
        const float v1 = sigf(wv[l][2] * a0 + wv[l][3] * a1 + hbv[l][1]);
        a0 = v0; a1 = v1;
      }
      stx(dout, ooff + (size_t)(b0 + bq * 16 + b) * NM + m, f, a0 * o0 + a1 * o1 + obv);
    }
  }
}

extern "C" void kernel_launch(void* const* d_in, const int* in_sizes, int n_in,
                              void* d_out, int out_size, void* d_ws, size_t ws_size,
                              hipStream_t stream) {
  const void* x   = d_in[0];
  const void* eps = d_in[1];
  const void* e1w = d_in[2];
  const void* e1b = d_in[3];
  const void* e2w = d_in[4];
  const void* e2b = d_in[5];
  const void* muw = d_in[6];
  const void* mub = d_in[7];
  const void* lvw = d_in[8];
  const void* lvb = d_in[9];
  const void* mfw = d_in[10];
  const void* mfb = d_in[11];
  const void* mhw = d_in[12];
  const void* mhb = d_in[13];
  const void* mow = d_in[14];
  const void* mob = d_in[15];
  const void* cfw = d_in[16];
  const void* cfb = d_in[17];
  const void* chw = d_in[18];
  const void* chb = d_in[19];
  const void* cow = d_in[20];
  const void* cob = d_in[21];

  // d_out element-space offsets (dtype-independent):
  //   out_x [0, B*M), out_lc [B*M, 2B*M), out_mu, out_lv.
  // h1 lives at out_x region, h2 at out_lc region (dead before dec overwrites).
  const size_t OFF_LC = (size_t)NB * NM;          // 4194304
  const size_t HUGE_SPLIT = 1u << 30;

  // ws: flag (4B, 256B-aligned pad) + zpre fp32 512KB + z fp32 256KB = ~768KB
  int*   flag = (int*)d_ws;
  float* zpre = (float*)((char*)d_ws + 256);
  float* z    = (float*)((char*)d_ws + 256 + (1u << 19));

  detect_dtype<<<dim3(1), 256, 0, stream>>>((const uint32_t*)x, flag);
  // enc1: h1 = relu(x @ e1w^T + e1b)   [1024 x 4096]
  gemm_tiled<1, 0><<<dim3(16, 64), 256, 0, stream>>>(
      x, 0, e1w, e1w, HUGE_SPLIT, e1b, d_out, 0, nullptr, NM, NM, flag);
  // enc2: h2 = relu(h1 @ e2w^T + e2b)  [1024 x 4096]
  gemm_tiled<1, 0><<<dim3(16, 64), 256, 0, stream>>>(
      d_out, 0, e2w, e2w, HUGE_SPLIT, e2b, d_out, OFF_LC, nullptr, NM, NM, flag);
  // mu/lv pre-activations: zpre = h2 @ [muw;lvw]^T  [1024 x 128] fp32
  gemm_tiled<0, 1><<<dim3(16, 2), 256, 0, stream>>>(
      d_out, OFF_LC, muw, lvw, NZ, nullptr, nullptr, 0, zpre, NM, 128, flag);
  zfin<<<dim3(256), 256, 0, stream>>>(zpre, eps, mub, lvb, d_out, z, flag);
  dec_fused<<<dim3(16, 16), 256, 0, stream>>>(z, mfw, mfb, mhw, mhb, mow, mob,
                                              d_out, 0, flag);
  dec_fused<<<dim3(16, 16), 256, 0, stream>>>(z, cfw, cfb, chw, chb, cow, cob,
                                              d_out, OFF_LC, flag);
}

// Round 5
// 610.714 us; speedup vs baseline: 3.5443x; 3.5443x over previous
//
#include <hip/hip_runtime.h>
#include <hip/hip_bf16.h>
#include <stdint.h>

typedef __hip_bfloat16 bf16;
typedef __bf16 bf16x8 __attribute__((ext_vector_type(8)));
typedef float f32x4 __attribute__((ext_vector_type(4)));

#define NB 1024
#define NM 4096
#define NZ 64
#define NH 8192

__device__ __forceinline__ float bf2f(bf16 x) { return __bfloat162float(x); }
__device__ __forceinline__ bf16 f2bf(float x) { return __float2bfloat16(x); }
__device__ __forceinline__ float sigf(float x) { return 1.f / (1.f + __expf(-x)); }

// fp32 x -> bf16 (4 elements/thread)
__global__ __launch_bounds__(256) void cvt_f32_bf16(const float* __restrict__ src,
                                                    bf16* __restrict__ dst, int n4) {
  const int i = blockIdx.x * 256 + threadIdx.x;
  if (i >= n4) return;
  const float4 v = ((const float4*)src)[i];
  bf16 o[4] = {f2bf(v.x), f2bf(v.y), f2bf(v.z), f2bf(v.w)};
  *(short4*)&dst[i * 4] = *(short4*)o;
}

__global__ void zero_f32(float* p, int n) {
  int i = blockIdx.x * blockDim.x + threadIdx.x;
  if (i < n) p[i] = 0.f;
}

// ---------------------------------------------------------------------------
// MFMA NT GEMM: C[r,c] = relu( sum_k A[r,k]*W[c,k] + bias[c] )
// A bf16 (pre-converted), W fp32 (converted in staging), bias fp32, C bf16.
// Tile 128x128, BK=64, 512 threads = 8 waves, wave -> 32x64 C sub-tile.
// Fragment layouts per m89/m91-verified ladder.
// ---------------------------------------------------------------------------
__global__ __launch_bounds__(512) void gemm_nt(const bf16* __restrict__ A,
                                               const float* __restrict__ W,
                                               const float* __restrict__ bias,
                                               bf16* __restrict__ C,
                                               int K, int N) {
  __shared__ __attribute__((aligned(16))) bf16 smA[128 * 64];
  __shared__ __attribute__((aligned(16))) bf16 smB[128 * 64];
  const int tid  = threadIdx.x;
  const int lane = tid & 63;
  const int w    = tid >> 6;   // 0..7
  const int wr   = w >> 1;     // 0..3 : 32-row group
  const int wc   = w & 1;      // 0..1 : 64-col group
  const int row0 = blockIdx.x * 128;
  const int col0 = blockIdx.y * 128;

  f32x4 acc[2][4];
#pragma unroll
  for (int i = 0; i < 2; i++)
#pragma unroll
    for (int j = 0; j < 4; j++) acc[i][j] = (f32x4){0.f, 0.f, 0.f, 0.f};

  for (int k0 = 0; k0 < K; k0 += 64) {
    // stage to registers (A: 16B bf16 loads; W: 2x16B fp32 loads + cvt)
    bf16x8 va[2], vb[2];
#pragma unroll
    for (int c = 0; c < 2; c++) {
      const int V = tid * 2 + c;          // 0..1023 : 16B LDS-vector id
      const int r  = V >> 3;              // tile row 0..127
      const int ko = (V & 7) * 8;         // k element offset 0..56
      va[c] = *(const bf16x8*)(A + (size_t)(row0 + r) * K + (k0 + ko));
      const float4 w0 = *(const float4*)(W + (size_t)(col0 + r) * K + (k0 + ko));
      const float4 w1 = *(const float4*)(W + (size_t)(col0 + r) * K + (k0 + ko + 4));
      bf16 t[8] = {f2bf(w0.x), f2bf(w0.y), f2bf(w0.z), f2bf(w0.w),
                   f2bf(w1.x), f2bf(w1.y), f2bf(w1.z), f2bf(w1.w)};
      vb[c] = *(bf16x8*)t;
    }
    __syncthreads();   // previous tile's LDS reads done
#pragma unroll
    for (int c = 0; c < 2; c++) {
      const int V = tid * 2 + c;
      const int r  = V >> 3;
      const int ko = (V & 7) * 8;
      *(bf16x8*)&smA[r * 64 + ko] = va[c];
      *(bf16x8*)&smB[r * 64 + ko] = vb[c];
    }
    __syncthreads();   // tile visible

#pragma unroll
    for (int ks = 0; ks < 64; ks += 32) {
      const int koff = ks + (lane >> 4) * 8;   // A/B frag: [m|n = lane&15][k = quad*8+j]
      bf16x8 af[2], bfr[4];
#pragma unroll
      for (int i = 0; i < 2; i++)
        af[i] = *(const bf16x8*)&smA[(wr * 32 + i * 16 + (lane & 15)) * 64 + koff];
#pragma unroll
      for (int j = 0; j < 4; j++)
        bfr[j] = *(const bf16x8*)&smB[(wc * 64 + j * 16 + (lane & 15)) * 64 + koff];
#pragma unroll
      for (int i = 0; i < 2; i++)
#pragma unroll
        for (int j = 0; j < 4; j++)
          acc[i][j] = __builtin_amdgcn_mfma_f32_16x16x32_bf16(af[i], bfr[j], acc[i][j], 0, 0, 0);
    }
  }

  // C/D layout: col = lane&15, row = (lane>>4)*4 + t   [m89-verified]
#pragma unroll
  for (int i = 0; i < 2; i++) {
#pragma unroll
    for (int j = 0; j < 4; j++) {
      const int cc = col0 + wc * 64 + j * 16 + (lane & 15);
      const float bs = bias[cc];
#pragma unroll
      for (int t = 0; t < 4; t++) {
        const int rr = row0 + wr * 32 + i * 16 + (lane >> 4) * 4 + t;
        float v = acc[i][j][t] + bs;
        v = v > 0.f ? v : 0.f;   // relu (both encoder layers)
        C[(size_t)rr * N + cc] = f2bf(v);
      }
    }
  }
}

// ---------------------------------------------------------------------------
// mu/logvar split-K: zpre[b, 0..63]=mu-dot, [64..127]=lv-dot (fp32 atomics).
// A = h2 bf16, weights fp32. grid (16 b-tiles, 16 k-chunks of 256), block 256.
// ---------------------------------------------------------------------------
__global__ __launch_bounds__(256) void mulv_splitk(const bf16* __restrict__ h2,
                                                   const float* __restrict__ muw,
                                                   const float* __restrict__ lvw,
                                                   float* __restrict__ zpre) {
  __shared__ float sA[32][64];    // [k][b]
  __shared__ float sW[32][128];   // [k][j]
  const int tid = threadIdx.x;
  const int b0 = blockIdx.x * 64;
  const int k0 = blockIdx.y * 256;
  const int tj = tid & 15;        // 8 j's each
  const int tb = tid >> 4;        // 4 b's each
  float acc[4][8];
#pragma unroll
  for (int i = 0; i < 4; i++)
#pragma unroll
    for (int j = 0; j < 8; j++) acc[i][j] = 0.f;

  const int lb = tid >> 2, lk = (tid & 3) * 8;    // h2 loader
  const int wj = tid >> 1, wk = (tid & 1) * 16;   // weight loader
  const float* wrow = (wj < 64) ? (muw + (size_t)wj * NM) : (lvw + (size_t)(wj - 64) * NM);

  for (int kc = 0; kc < 256; kc += 32) {
    __syncthreads();
    {
      const bf16* p = h2 + (size_t)(b0 + lb) * NM + (k0 + kc + lk);
#pragma unroll
      for (int i = 0; i < 8; i++) sA[lk + i][lb] = bf2f(p[i]);
      const float* q = wrow + (k0 + kc + wk);
#pragma unroll
      for (int i = 0; i < 16; i++) sW[wk + i][wj] = q[i];
    }
    __syncthreads();
#pragma unroll
    for (int k = 0; k < 32; k++) {
      float av[4], wv[8];
#pragma unroll
      for (int i = 0; i < 4; i++) av[i] = sA[k][tb * 4 + i];
#pragma unroll
      for (int j = 0; j < 8; j++) wv[j] = sW[k][tj * 8 + j];
#pragma unroll
      for (int i = 0; i < 4; i++)
#pragma unroll
        for (int j = 0; j < 8; j++) acc[i][j] += av[i] * wv[j];
    }
  }
#pragma unroll
  for (int i = 0; i < 4; i++)
#pragma unroll
    for (int j = 0; j < 8; j++)
      atomicAdd(&zpre[(size_t)(b0 + tb * 4 + i) * 128 + tj * 8 + j], acc[i][j]);
}

// mu/lv bias + reparameterization; fp32 outputs, fp32 z (ws)
__global__ void zfin(const float* __restrict__ zpre, const float* __restrict__ eps,
                     const float* __restrict__ mub, const float* __restrict__ lvb,
                     float* __restrict__ out_mu, float* __restrict__ out_lv,
                     float* __restrict__ z) {
  const int i = blockIdx.x * 256 + threadIdx.x;   // B*Z = 65536
  const int b = i >> 6, j = i & 63;
  const float mu = zpre[(size_t)b * 128 + j] + mub[j];
  const float lv = zpre[(size_t)b * 128 + 64 + j] + lvb[j];
  const float zz = mu + expf(0.5f * lv) * eps[i];
  out_mu[i] = mu;
  out_lv[i] = lv;
  z[i] = zz;
}

// ---------------------------------------------------------------------------
// Fused decoder branch: fulcon sigmoid + two 2x2 sigmoid block layers + out dot.
// fw staged in LDS per mi-group (fixes 512B-stride uncoalesced global reads).
// Block = 64 b x 256 m; grid (16,16). All fp32.
// ---------------------------------------------------------------------------
__global__ __launch_bounds__(256) void dec_fused(
    const float* __restrict__ z,
    const float* __restrict__ fw, const float* __restrict__ fb,
    const float* __restrict__ hw, const float* __restrict__ hb,
    const float* __restrict__ ow, const float* __restrict__ ob,
    float* __restrict__ out) {
  __shared__ __attribute__((aligned(16))) float sZ[64][68];  // [k][b], 16B-aligned rows
  __shared__ float sFW[64][130];                             // [k][local fw row]
  const int tid = threadIdx.x;
  const int b0 = blockIdx.x * 64;
  const int m0 = blockIdx.y * 256;
  {
    const int r  = tid >> 2;          // b-row 0..63
    const int c0 = (tid & 3) * 16;    // k-chunk
    const float* p = z + (size_t)(b0 + r) * NZ + c0;
#pragma unroll
    for (int i = 0; i < 16; i++) sZ[c0 + i][r] = p[i];
  }

  const int bq = tid >> 6;   // 0..3 : 16-b group
  const int tm = tid & 63;   // lane -> consecutive m

  for (int mi = 0; mi < 4; mi++) {
    const int mb = m0 + mi * 64;        // m-base of this group
    __syncthreads();                    // sFW reuse + (mi==0) sZ ready
    {
      // stage fw rows [2*mb, 2*mb+128) x 64k, transposed: sFW[k][localrow]
      const int R0 = 2 * mb;
#pragma unroll
      for (int q = 0; q < 8; q++) {
        const int v = tid + q * 256;        // 0..2047 float4-ids
        const int grow = v >> 4;            // 0..127
        const int gk = (v & 15) * 4;
        const float4 f4 = *(const float4*)&fw[(size_t)(R0 + grow) * NZ + gk];
        sFW[gk + 0][grow] = f4.x;
        sFW[gk + 1][grow] = f4.y;
        sFW[gk + 2][grow] = f4.z;
        sFW[gk + 3][grow] = f4.w;
      }
    }
    __syncthreads();

    const int m = mb + tm;
    float acc0[16], acc1[16];
    const float bb0 = fb[2 * m], bb1 = fb[2 * m + 1];
#pragma unroll
    for (int b = 0; b < 16; b++) { acc0[b] = bb0; acc1[b] = bb1; }
#pragma unroll 8
    for (int k = 0; k < 64; k++) {
      const float2 wv2 = *(const float2*)&sFW[k][2 * tm];   // 8B-aligned
      const float4 z0 = *(const float4*)&sZ[k][bq * 16 + 0];
      const float4 z1 = *(const float4*)&sZ[k][bq * 16 + 4];
      const float4 z2 = *(const float4*)&sZ[k][bq * 16 + 8];
      const float4 z3 = *(const float4*)&sZ[k][bq * 16 + 12];
      const float zv[16] = {z0.x, z0.y, z0.z, z0.w, z1.x, z1.y, z1.z, z1.w,
                            z2.x, z2.y, z2.z, z2.w, z3.x, z3.y, z3.z, z3.w};
#pragma unroll
      for (int b = 0; b < 16; b++) {
        acc0[b] += zv[b] * wv2.x;
        acc1[b] += zv[b] * wv2.y;
      }
    }
    // tail: 2x2 sigmoid chain + output dot (coalesced float4/float2 weight reads)
    float wv[2][4], hbv[2][2];
#pragma unroll
    for (int l = 0; l < 2; l++) {
      const float4 wp = *(const float4*)&hw[((size_t)l * NM + m) * 4];  // [v][w] 2x2
      wv[l][0] = wp.x; wv[l][1] = wp.y; wv[l][2] = wp.z; wv[l][3] = wp.w;
      const float2 hb2 = *(const float2*)&hb[(size_t)l * NH + 2 * m];
      hbv[l][0] = hb2.x; hbv[l][1] = hb2.y;
    }
    const float2 o2 = *(const float2*)&ow[2 * m];
    const float obv = ob[m];
#pragma unroll
    for (int b = 0; b < 16; b++) {
      float a0 = sigf(acc0[b]), a1 = sigf(acc1[b]);
#pragma unroll
      for (int l = 0; l < 2; l++) {
        const float v0 = sigf(wv[l][0] * a0 + wv[l][1] * a1 + hbv[l][0]);
        const float v1 = sigf(wv[l][2] * a0 + wv[l][3] * a1 + hbv[l][1]);
        a0 = v0; a1 = v1;
      }
      out[(size_t)(b0 + bq * 16 + b) * NM + m] = a0 * o2.x + a1 * o2.y + obv;
    }
  }
}

extern "C" void kernel_launch(void* const* d_in, const int* in_sizes, int n_in,
                              void* d_out, int out_size, void* d_ws, size_t ws_size,
                              hipStream_t stream) {
  const float* x   = (const float*)d_in[0];
  const float* eps = (const float*)d_in[1];
  const float* e1w = (const float*)d_in[2];
  const float* e1b = (const float*)d_in[3];
  const float* e2w = (const float*)d_in[4];
  const float* e2b = (const float*)d_in[5];
  const float* muw = (const float*)d_in[6];
  const float* mub = (const float*)d_in[7];
  const float* lvw = (const float*)d_in[8];
  const float* lvb = (const float*)d_in[9];
  const float* mfw = (const float*)d_in[10];
  const float* mfb = (const float*)d_in[11];
  const float* mhw = (const float*)d_in[12];
  const float* mhb = (const float*)d_in[13];
  const float* mow = (const float*)d_in[14];
  const float* mob = (const float*)d_in[15];
  const float* cfw = (const float*)d_in[16];
  const float* cfb = (const float*)d_in[17];
  const float* chw = (const float*)d_in[18];
  const float* chb = (const float*)d_in[19];
  const float* cow = (const float*)d_in[20];
  const float* cob = (const float*)d_in[21];

  // d_out regions (fp32 elements): out_x [0,4M), out_lc [4M,8M), mu, lv.
  // bf16 intermediates overlay dead byte-ranges:
  //   h1 bf16 @ bytes [0,8M)      (dead after enc2; dec-mean overwrites)
  //   xb bf16 @ bytes [16M,24M)   (dead after enc1)
  //   h2 bf16 @ bytes [16M,24M)   (overwrites xb; dead after mulv; dec-cov overwrites)
  char* ob_ = (char*)d_out;
  float* out_x  = (float*)ob_;
  float* out_lc = (float*)(ob_ + (16u << 20));
  float* out_mu = out_x + (size_t)2 * NB * NM;
  float* out_lv = out_mu + (size_t)NB * NZ;
  bf16* h1 = (bf16*)ob_;
  bf16* xb = (bf16*)(ob_ + (16u << 20));
  bf16* h2 = xb;

  // ws: zpre fp32 512KB + z fp32 256KB = 768KB (round-4-proven budget)
  float* zpre = (float*)d_ws;
  float* z    = (float*)((char*)d_ws + (1u << 19));

  cvt_f32_bf16<<<dim3(4096), 256, 0, stream>>>(x, xb, NB * NM / 4);
  zero_f32<<<dim3(512), 256, 0, stream>>>(zpre, NB * 128);
  gemm_nt<<<dim3(8, 32), 512, 0, stream>>>(xb, e1w, e1b, h1, NM, NM);
  gemm_nt<<<dim3(8, 32), 512, 0, stream>>>(h1, e2w, e2b, h2, NM, NM);
  mulv_splitk<<<dim3(16, 16), 256, 0, stream>>>(h2, muw, lvw, zpre);
  zfin<<<dim3(256), 256, 0, stream>>>(zpre, eps, mub, lvb, out_mu, out_lv, z);
  dec_fused<<<dim3(16, 16), 256, 0, stream>>>(z, mfw, mfb, mhw, mhb, mow, mob, out_x);
  dec_fused<<<dim3(16, 16), 256, 0, stream>>>(z, cfw, cfb, chw, chb, cow, cob, out_lc);
}